// Round 12
// baseline (751.801 us; speedup 1.0000x reference)
//
#include <hip/hip_runtime.h>
#include <cstdint>
#include <cstddef>

#define NB 8
#define NPTS 8192
#define S_TOT 512
#define NSAMP 64
#define DFEAT 64
#define INCH 67
#define SLOTS 17
#define CCAP (SLOTS * 256)   // 4352 compacted slots per (b,grp)

typedef __attribute__((ext_vector_type(8))) short v8s;
typedef __attribute__((ext_vector_type(4))) short v4s;
typedef __attribute__((ext_vector_type(4))) float v4f;

// exact (numpy-matching) squared distance: (a-b) per component, square, sum as (x+y)+z
__device__ __forceinline__ float d2_exact(float ax, float ay, float az,
                                          float bx, float by, float bz) {
    float dx = __fsub_rn(ax, bx);
    float dy = __fsub_rn(ay, by);
    float dz = __fsub_rn(az, bz);
    return __fadd_rn(__fadd_rn(__fmul_rn(dx, dx), __fmul_rn(dy, dy)), __fmul_rn(dz, dz));
}

// fp32 -> bf16 round-to-nearest-even
__device__ __forceinline__ unsigned short f2b(float f) {
    unsigned u = __float_as_uint(f);
    return (unsigned short)((u + 0x7fffu + ((u >> 16) & 1u)) >> 16);
}

template <int CTRL>
__device__ __forceinline__ unsigned long long dpp_max_u64(unsigned long long k) {
    int lo = (int)(unsigned)(k & 0xffffffffull);
    int hi = (int)(unsigned)(k >> 32);
    int slo = __builtin_amdgcn_update_dpp(lo, lo, CTRL, 0xf, 0xf, false);
    int shi = __builtin_amdgcn_update_dpp(hi, hi, CTRL, 0xf, 0xf, false);
    unsigned long long o = ((unsigned long long)(unsigned)shi << 32) | (unsigned)slo;
    return (o > k) ? o : k;
}

// ---------------------------------------------------------------------------
// FRONT kernel: blocks 0..15 = fps_compact (R5-R10-verified logic);
// blocks 16..1039 = points transpose fp32[B,64,N] -> bf16[B,N,64];
// blocks 1040..1075 = weight pack to MFMA B-frag order.
// ---------------------------------------------------------------------------
__global__ __launch_bounds__(1024) void front_kernel(
    const float* __restrict__ xyz, const float* __restrict__ attn,
    float4* __restrict__ cxyz, int* __restrict__ hdr,
    const float* __restrict__ pts, unsigned short* __restrict__ ptsTh,
    const float* __restrict__ w0, const float* __restrict__ w1,
    const float* __restrict__ w2, unsigned short* __restrict__ wp)
{
    int blk = blockIdx.x;
    int tid = threadIdx.x;

    if (blk < 16) {
        // ---------------- fps_compact ----------------
        int b = blk >> 1, grp = blk & 1;
        const float* xb = xyz + (size_t)b * 3 * NPTS;
        const float* ab = attn + (size_t)b * NPTS;
        float4* c4 = cxyz + (size_t)blk * CCAP;

        int lane = tid & 63, wid = tid >> 6;
        int n0 = tid * 8;

        __shared__ int s_repmin;
        __shared__ int s_ws[16];
        if (tid == 0) s_repmin = NPTS;
        __syncthreads();

        float av[8];
        *(float4*)&av[0] = *(const float4*)(ab + n0);
        *(float4*)&av[4] = *(const float4*)(ab + n0 + 4);
        int cnt = 0, mymin = NPTS;
        bool keep[8];
#pragma unroll
        for (int j = 0; j < 8; j++) {
            keep[j] = grp ? (av[j] == 0.0f) : (av[j] != 0.0f);
            cnt += keep[j] ? 1 : 0;
            if (!keep[j] && n0 + j < mymin) mymin = n0 + j;
        }
        if (mymin < NPTS) atomicMin(&s_repmin, mymin);

        int incl = cnt;
#pragma unroll
        for (int off = 1; off <= 32; off <<= 1) {
            int t = __shfl_up(incl, off);
            if (lane >= off) incl += t;
        }
        if (lane == 63) s_ws[wid] = incl;
        __syncthreads();
        int woff = 0, tot = 0;
#pragma unroll
        for (int w = 0; w < 16; w++) { if (w < wid) woff += s_ws[w]; tot += s_ws[w]; }
        int pos = woff + incl - cnt;
        int rm = s_repmin;
        int rm_eff = (rm < NPTS) ? rm : 0x7fffffff;

        float xv[8], yv[8], zv[8];
        *(float4*)&xv[0] = *(const float4*)(xb + n0);
        *(float4*)&xv[4] = *(const float4*)(xb + n0 + 4);
        *(float4*)&yv[0] = *(const float4*)(xb + NPTS + n0);
        *(float4*)&yv[4] = *(const float4*)(xb + NPTS + n0 + 4);
        *(float4*)&zv[0] = *(const float4*)(xb + 2 * NPTS + n0);
        *(float4*)&zv[4] = *(const float4*)(xb + 2 * NPTS + n0 + 4);
#pragma unroll
        for (int j = 0; j < 8; j++) {
            if (keep[j]) {
                int fin = pos + ((n0 + j > rm_eff) ? 1 : 0);
                if (fin < CCAP)
                    c4[fin] = make_float4(xv[j], yv[j], zv[j], 0.0f);
                pos++;
            }
        }
        if (tid == 0) {
            int M = tot;
            if (rm < NPTS) {
                if (rm < CCAP)
                    c4[rm] = make_float4(__fmul_rn(0.0f, xb[rm]),
                                         __fmul_rn(0.0f, xb[NPTS + rm]),
                                         __fmul_rn(0.0f, xb[2 * NPTS + rm]), 0.0f);
                M++;
            }
            hdr[blk * 2] = M;
            hdr[blk * 2 + 1] = (rm < NPTS) ? rm : -1;
        }
    } else if (blk < 16 + 1024) {
        // ---------------- points transpose ----------------
        __shared__ float t[64][65];
        int blk2 = blk - 16;
        int b = blk2 >> 7;
        int n0 = (blk2 & 127) * 64;
        int tx = tid & 63, ty = tid >> 6;   // ty in 0..15
        for (int c = ty; c < 64; c += 16)
            t[c][tx] = pts[((size_t)b * DFEAT + c) * NPTS + n0 + tx];
        __syncthreads();
        for (int r = ty; r < 64; r += 16)
            ptsTh[((size_t)b * NPTS + n0 + r) * DFEAT + tx] = f2b(t[tx][r]);
    } else if (tid < 64) {
        // ---------------- weight pack ----------------
        int t = blk - (16 + 1024), l = tid;
        int kq = (l >> 4) * 8, n16 = l & 15;
        unsigned short o[8];
#pragma unroll
        for (int j = 0; j < 8; j++) {
            float v;
            if (t < 12) {
                int kt = t >> 2, nt = t & 3;
                int k = kt * 32 + kq + j, n = nt * 16 + n16;
                v = (k < 64) ? w0[n * INCH + 3 + k] : (k < 67 ? w0[n * INCH + (k - 64)] : 0.0f);
            } else if (t < 20) {
                int tt = t - 12, kt = tt >> 2, nt = tt & 3;
                v = w1[(nt * 16 + n16) * 64 + kt * 32 + kq + j];
            } else {
                int tt = t - 20, kt = tt >> 3, nt = tt & 7;
                v = w2[(nt * 16 + n16) * 64 + kt * 32 + kq + j];
            }
            o[j] = f2b(v);
        }
        *(v8s*)&wp[(size_t)t * 512 + l * 8] = *(v8s*)o;
    }
}

// ---------------------------------------------------------------------------
// FPS stage 2 v7: R6's update/fold/DPP (byte-identical — proven no-spill,
// VGPR 88) + spin-poll sync with the R11 RACE FIXED:
//   producer lane 63: volatile store KEY, then volatile store STAMP=k
//     (separate arrays, separate stores; same-wave DS ops execute and become
//      visible in order)
//   consumer: volatile-poll the 4 STAMPS until all == k, THEN read the 4 keys
//     (volatile preserves program order; stamp==k happens-after key write ->
//      key is current. R11 read key before stamp — stale-key race.)
// Deadlock-free: every wave produces before polling; parity-buffer reuse at
// k+2 requires all waves passed the k-poll. Stamps unique per k (no ABA).
// Outputs stored directly to global (no barrier -> no drain).
// ---------------------------------------------------------------------------
__global__ __launch_bounds__(256, 1) void fps_iter(
    const float* __restrict__ attn,
    const float4* __restrict__ cxyz,
    const int* __restrict__ hdr,
    float* __restrict__ out0, float* __restrict__ out2)
{
    int blk = blockIdx.x;
    int b = blk >> 1, grp = blk & 1;
    int K = grp ? 384 : 128;
    int soff = grp ? 128 : 0;
    int M = hdr[blk * 2];
    int repslot = hdr[blk * 2 + 1];
    if (M > CCAP) return;             // fps_kernel fallback covers this block
    int tid = threadIdx.x, lane = tid & 63, wid = tid >> 6;

    const float4* cb = cxyz + (size_t)blk * CCAP;
    __shared__ float4 sc[CCAP];
    __shared__ __align__(16) unsigned long long s_key[2][4];
    __shared__ int s_stamp[2][4];

    if (tid < 8) s_stamp[tid >> 2][tid & 3] = -1;   // != any k

    float px[SLOTS], py[SLOTS], pz[SLOTS], md[SLOTS];
#pragma unroll
    for (int i = 0; i < SLOTS; i++) {
        int sl = i * 256 + tid;
        bool v = sl < M;
        float4 c = v ? cb[sl] : make_float4(0.f, 0.f, 0.f, 0.f);
        px[i] = c.x; py[i] = c.y; pz[i] = c.z;
        sc[sl] = c;
        md[i] = v ? 1e10f : -1.0f;
    }
    __syncthreads();   // ONLY barrier: orders sc[] fill + stamp init across waves

    float4 c0 = cb[0];
    float lx = c0.x, ly = c0.y, lz = c0.z;
    float a_last = attn[(size_t)b * NPTS];
    float kept_a = grp ? 0.0f : 1.0f;
    float rep_a  = grp ? 1.0f : 0.0f;

    for (int k = 0; k < K; k++) {
        if (tid == 0) {
            int sg = soff + k;
            out0[(size_t)b * 3 * S_TOT + sg] = lx;
            out0[(size_t)b * 3 * S_TOT + S_TOT + sg] = ly;
            out0[(size_t)b * 3 * S_TOT + 2 * S_TOT + sg] = lz;
            out2[(size_t)b * S_TOT + sg] = a_last;
        }
        if (k == K - 1) break;

        // update + key-only fold (byte-identical to R6: exact + no spill)
        float bv = -1.0f; int bslot = 0x7fffffff;
#pragma unroll
        for (int i = 0; i < SLOTS; i++) {
            float d2 = d2_exact(px[i], py[i], pz[i], lx, ly, lz);
            md[i] = fminf(md[i], d2);
            int sl = i * 256 + tid;
            bool w = (md[i] > bv) || ((md[i] == bv) && (sl < bslot));
            bv = w ? md[i] : bv;
            bslot = w ? sl : bslot;
        }
        unsigned long long key = (bv >= 0.0f)
            ? (((unsigned long long)__float_as_uint(bv) << 32) | (unsigned)(~bslot))
            : 0ull;
        key = dpp_max_u64<0x111>(key);
        key = dpp_max_u64<0x112>(key);
        key = dpp_max_u64<0x114>(key);
        key = dpp_max_u64<0x118>(key);
        key = dpp_max_u64<0x142>(key);
        key = dpp_max_u64<0x143>(key);    // lane 63 = wave max
        int buf = k & 1;
        if (lane == 63) {
            volatile unsigned long long* kp = &s_key[buf][wid];
            volatile int* sp = &s_stamp[buf][wid];
            *kp = key;     // key first...
            *sp = k;       // ...stamp second (same-wave DS ops ordered)
        }

        // poll STAMPS only; keys are read strictly after all stamps == k
        {
            volatile int* sp = &s_stamp[buf][0];
            for (;;) {
                int s0 = sp[0], s1 = sp[1], s2 = sp[2], s3 = sp[3];
                if (s0 == k && s1 == k && s2 == k && s3 == k) break;
            }
        }
        volatile unsigned long long* kp = &s_key[buf][0];
        unsigned long long kk0 = kp[0], kk1 = kp[1], kk2 = kp[2], kk3 = kp[3];

        unsigned long long m01 = (kk0 > kk1) ? kk0 : kk1;
        unsigned long long m23 = (kk2 > kk3) ? kk2 : kk3;
        unsigned long long g = (m01 > m23) ? m01 : m23;
        int wslot = (int)(~(unsigned)g);
        float4 wc = sc[wslot];            // ds_read_b128, broadcast (sc read-only)
        lx = wc.x; ly = wc.y; lz = wc.z;
        a_last = (wslot == repslot) ? rep_a : kept_a;
    }
}

// ---------------------------------------------------------------------------
// Fallback FPS (unchanged): only if a block overflowed CCAP or ws too small.
// ---------------------------------------------------------------------------
__global__ __launch_bounds__(1024, 1) void fps_kernel(
    const float* __restrict__ xyz, const float* __restrict__ attn,
    const int* __restrict__ hdr,
    float* __restrict__ out0, float* __restrict__ out2)
{
    int blk = blockIdx.x;
    if (hdr != nullptr && hdr[blk * 2] <= CCAP) return;
    int b = blk >> 1, grp = blk & 1;
    int K = grp ? 384 : 128;
    int soff = grp ? 128 : 0;
    int tid = threadIdx.x, lane = tid & 63, wid = tid >> 6;
    const float* xb = xyz + (size_t)b * 3 * NPTS;
    const float* ab = attn + (size_t)b * NPTS;

    float px[8], py[8], pz[8], md[8];
#pragma unroll
    for (int i = 0; i < 8; i++) {
        int n = tid + i * 1024;
        float a = ab[n];
        float f = grp ? __fsub_rn(1.0f, a) : a;
        px[i] = __fmul_rn(f, xb[n]);
        py[i] = __fmul_rn(f, xb[NPTS + n]);
        pz[i] = __fmul_rn(f, xb[2 * NPTS + n]);
        md[i] = 1e10f;
    }
    __shared__ unsigned long long s_red[2][16];
    float a_last = ab[0];
    float f0 = grp ? __fsub_rn(1.0f, a_last) : a_last;
    float lx = __fmul_rn(f0, xb[0]);
    float ly = __fmul_rn(f0, xb[NPTS]);
    float lz = __fmul_rn(f0, xb[2 * NPTS]);

    for (int k = 0; k < K; k++) {
        if (tid == 0) {
            int sg = soff + k;
            out0[(size_t)b * 3 * S_TOT + sg] = lx;
            out0[(size_t)b * 3 * S_TOT + S_TOT + sg] = ly;
            out0[(size_t)b * 3 * S_TOT + 2 * S_TOT + sg] = lz;
            out2[(size_t)b * S_TOT + sg] = a_last;
        }
        if (k == K - 1) break;
        float bv = -1.0f; int bi = 0;
#pragma unroll
        for (int i = 0; i < 8; i++) {
            float d2 = d2_exact(px[i], py[i], pz[i], lx, ly, lz);
            md[i] = fminf(md[i], d2);
            if (md[i] > bv) { bv = md[i]; bi = tid + i * 1024; }
        }
        unsigned long long best =
            ((unsigned long long)__float_as_uint(bv) << 32) | (unsigned)(~bi);
#pragma unroll
        for (int off = 32; off >= 1; off >>= 1) {
            unsigned long long o = __shfl_down(best, off);
            best = (o > best) ? o : best;
        }
        if (lane == 0) s_red[k & 1][wid] = best;
        __syncthreads();
        unsigned long long r = (lane < 16) ? s_red[k & 1][lane] : 0ull;
#pragma unroll
        for (int off = 8; off >= 1; off >>= 1) {
            unsigned long long o = __shfl_down(r, off);
            r = (o > r) ? o : r;
        }
        r = __shfl(r, 0);
        int n = (int)(~(unsigned)r);
        a_last = ab[n];
        float fl = grp ? __fsub_rn(1.0f, a_last) : a_last;
        lx = __fmul_rn(fl, xb[n]);
        ly = __fmul_rn(fl, xb[NPTS + n]);
        lz = __fmul_rn(fl, xb[2 * NPTS + n]);
    }
}

// ---------------------------------------------------------------------------
// Ball query + MFMA MLP + max. UNCHANGED from R10 (verified absmax 0.015625;
// LDS union 13.6 KB, 11 blocks/CU).
// ---------------------------------------------------------------------------
__global__ __launch_bounds__(64, 2) void ball_mlp_mfma(
    const float* __restrict__ xyz,
    const unsigned short* __restrict__ ptsTh,
    const unsigned short* __restrict__ wp,
    const float* __restrict__ b0, const float* __restrict__ b1,
    const float* __restrict__ b2,
    const float* __restrict__ out0,
    float* __restrict__ out1)
{
    const float R2 = (float)(0.4 * 0.4);   // 0x3E23D70A — NOT 0.4f*0.4f
    int q = blockIdx.x;
    int b = q >> 9;
    int sg = q & 511;
    int lane = threadIdx.x;
    int col = lane & 15, quad = lane >> 4, kq = quad * 8;

    const float* xb = xyz + (size_t)b * 3 * NPTS;
    float qx = out0[(size_t)b * 3 * S_TOT + sg];
    float qy = out0[(size_t)b * 3 * S_TOT + S_TOT + sg];
    float qz = out0[(size_t)b * 3 * S_TOT + 2 * S_TOT + sg];

    __shared__ int s_idx[NSAMP];
    __shared__ __align__(16) short sBuf[64 * 104];           // 13312 B union
    unsigned long long* s_mask = (unsigned long long*)sBuf;  // phase A: 1 KB

    // ---- phase 1: independent ballots ----
#pragma unroll 8
    for (int j = 0; j < 128; j++) {
        int n = j * 64 + lane;
        float d2 = d2_exact(qx, qy, qz, xb[n], xb[NPTS + n], xb[2 * NPTS + n]);
        unsigned long long m = __ballot(d2 < R2);
        if (lane == 0) s_mask[j] = m;
    }

    // ---- phase 2: prefix over 128 chunk popcounts ----
    unsigned long long m0 = s_mask[lane];
    unsigned long long m1 = s_mask[64 + lane];
    int c0 = (int)__popcll(m0), c1 = (int)__popcll(m1);
    int i0 = c0;
#pragma unroll
    for (int off = 1; off <= 32; off <<= 1) {
        int t = __shfl_up(i0, off);
        if (lane >= off) i0 += t;
    }
    int T0 = __shfl(i0, 63);
    int i1 = c1;
#pragma unroll
    for (int off = 1; off <= 32; off <<= 1) {
        int t = __shfl_up(i1, off);
        if (lane >= off) i1 += t;
    }
    int total = T0 + __shfl(i1, 63);
    int p0 = i0 - c0;
    int p1 = T0 + i1 - c1;

    // ---- phase 3: bit expansion into s_idx (global chunk/bit order) ----
    {
        int base = p0, org = lane * 64;
        while (m0 && base < NSAMP) {
            int bp = __ffsll((long long)m0) - 1;
            s_idx[base++] = org + bp;
            m0 &= m0 - 1;
        }
        base = p1; org = (64 + lane) * 64;
        while (m1 && base < NSAMP) {
            int bp = __ffsll((long long)m1) - 1;
            s_idx[base++] = org + bp;
            m1 &= m1 - 1;
        }
    }
    int cnt = (total > NSAMP) ? NSAMP : total;

    int nb = (lane < cnt) ? s_idx[lane] : -1;
    float nx_ = 0.f, ny_ = 0.f, nz_ = 0.f;
    if (nb >= 0) { nx_ = xb[nb]; ny_ = xb[NPTS + nb]; nz_ = xb[2 * NPTS + nb]; }
    float fx = nx_ - qx, fy = ny_ - qy, fz = nz_ - qz;   // pad rows: -new_xyz
    int row = (nb < 0) ? (NPTS - 1) : nb;                // torch -1 wraps to last

    // ---- stage X1 row (stride 104; masks dead, safe to overwrite) ----
    {
        const unsigned short* ph = ptsTh + ((size_t)b * NPTS + row) * DFEAT;
        short* xr = &sBuf[lane * 104];
#pragma unroll
        for (int i = 0; i < 8; i++)
            *(v8s*)(xr + i * 8) = *(const v8s*)(ph + i * 8);
#pragma unroll
        for (int i = 0; i < 5; i++)
            *(v8s*)(xr + 64 + i * 8) = (v8s)0;
        v4s xyzp;
        xyzp[0] = (short)f2b(fx); xyzp[1] = (short)f2b(fy);
        xyzp[2] = (short)f2b(fz); xyzp[3] = 0;
        *(v4s*)(xr + 64) = xyzp;
    }

    const v8s* wpv = (const v8s*)wp;

    // ---- layer 1: [64x96] x [96x64], 3 K-steps ----
    v4f acc[4][4];
#pragma unroll
    for (int nt = 0; nt < 4; nt++) {
        float bb = b0[nt * 16 + col];
#pragma unroll
        for (int mt = 0; mt < 4; mt++) acc[mt][nt] = (v4f){bb, bb, bb, bb};
    }
#pragma unroll
    for (int kt = 0; kt < 3; kt++) {
        v8s bf[4];
#pragma unroll
        for (int nt = 0; nt < 4; nt++) bf[nt] = wpv[(kt * 4 + nt) * 64 + lane];
#pragma unroll
        for (int mt = 0; mt < 4; mt++) {
            v8s a = *(const v8s*)&sBuf[(mt * 16 + col) * 104 + kt * 32 + kq];
#pragma unroll
            for (int nt = 0; nt < 4; nt++)
                acc[mt][nt] = __builtin_amdgcn_mfma_f32_16x16x32_bf16(a, bf[nt], acc[mt][nt], 0, 0, 0);
        }
    }
#pragma unroll
    for (int mt = 0; mt < 4; mt++)
#pragma unroll
        for (int nt = 0; nt < 4; nt++)
#pragma unroll
            for (int r = 0; r < 4; r++)
                sBuf[(mt * 16 + quad * 4 + r) * 72 + nt * 16 + col] =
                    (short)f2b(fmaxf(acc[mt][nt][r], 0.0f));

    // ---- layer 2: [64x64] x [64x64], 2 K-steps ----
#pragma unroll
    for (int nt = 0; nt < 4; nt++) {
        float bb = b1[nt * 16 + col];
#pragma unroll
        for (int mt = 0; mt < 4; mt++) acc[mt][nt] = (v4f){bb, bb, bb, bb};
    }
#pragma unroll
    for (int kt = 0; kt < 2; kt++) {
        v8s bf[4];
#pragma unroll
        for (int nt = 0; nt < 4; nt++) bf[nt] = wpv[(12 + kt * 4 + nt) * 64 + lane];
#pragma unroll
        for (int mt = 0; mt < 4; mt++) {
            v8s a = *(const v8s*)&sBuf[(mt * 16 + col) * 72 + kt * 32 + kq];
#pragma unroll
            for (int nt = 0; nt < 4; nt++)
                acc[mt][nt] = __builtin_amdgcn_mfma_f32_16x16x32_bf16(a, bf[nt], acc[mt][nt], 0, 0, 0);
        }
    }
#pragma unroll
    for (int mt = 0; mt < 4; mt++)
#pragma unroll
        for (int nt = 0; nt < 4; nt++)
#pragma unroll
            for (int r = 0; r < 4; r++)
                sBuf[(mt * 16 + quad * 4 + r) * 72 + nt * 16 + col] =
                    (short)f2b(fmaxf(acc[mt][nt][r], 0.0f));

    // ---- layer 3: [64x64] x [64x128], two passes of 4 N-tiles ----
#pragma unroll
    for (int p = 0; p < 2; p++) {
#pragma unroll
        for (int nt = 0; nt < 4; nt++) {
            float bb = b2[(p * 4 + nt) * 16 + col];
#pragma unroll
            for (int mt = 0; mt < 4; mt++) acc[mt][nt] = (v4f){bb, bb, bb, bb};
        }
#pragma unroll
        for (int kt = 0; kt < 2; kt++) {
            v8s bf[4];
#pragma unroll
            for (int nt = 0; nt < 4; nt++)
                bf[nt] = wpv[(20 + kt * 8 + p * 4 + nt) * 64 + lane];
#pragma unroll
            for (int mt = 0; mt < 4; mt++) {
                v8s a = *(const v8s*)&sBuf[(mt * 16 + col) * 72 + kt * 32 + kq];
#pragma unroll
                for (int nt = 0; nt < 4; nt++)
                    acc[mt][nt] = __builtin_amdgcn_mfma_f32_16x16x32_bf16(a, bf[nt], acc[mt][nt], 0, 0, 0);
            }
        }
#pragma unroll
        for (int nt = 0; nt < 4; nt++) {
            float v = 0.0f;   // relu output >= 0
#pragma unroll
            for (int mt = 0; mt < 4; mt++)
#pragma unroll
                for (int r = 0; r < 4; r++)
                    v = fmaxf(v, acc[mt][nt][r]);
            v = fmaxf(v, __shfl_xor(v, 16));
            v = fmaxf(v, __shfl_xor(v, 32));
            if (lane < 16)
                out1[((size_t)(b * 128 + (p * 4 + nt) * 16 + lane)) * S_TOT + sg] = v;
        }
    }
}

// ---------------------------------------------------------------------------
// Fallback ball+MLP (no ws): unchanged from R6.
// ---------------------------------------------------------------------------
__global__ __launch_bounds__(64, 1) void ball_mlp_fb(
    const float* __restrict__ xyz, const float* __restrict__ pts,
    const float* __restrict__ w0, const float* __restrict__ b0,
    const float* __restrict__ w1, const float* __restrict__ b1,
    const float* __restrict__ w2, const float* __restrict__ b2,
    const float* __restrict__ out0, float* __restrict__ out1)
{
    const float R2 = (float)(0.4 * 0.4);
    int q = blockIdx.x;
    int b = q >> 9, sg = q & 511, lane = threadIdx.x;
    const float* xb = xyz + (size_t)b * 3 * NPTS;
    float qx = out0[(size_t)b * 3 * S_TOT + sg];
    float qy = out0[(size_t)b * 3 * S_TOT + S_TOT + sg];
    float qz = out0[(size_t)b * 3 * S_TOT + 2 * S_TOT + sg];

    __shared__ int s_idx[NSAMP];
    __shared__ float s_h[32 * 64];
    int cnt = 0;
    for (int base = 0; base < NPTS; base += 64) {
        int n = base + lane;
        float d2 = d2_exact(qx, qy, qz, xb[n], xb[NPTS + n], xb[2 * NPTS + n]);
        bool flag = d2 < R2;
        unsigned long long m = __ballot(flag);
        int pos = cnt + (int)__popcll(m & ((1ull << lane) - 1ull));
        if (flag && pos < NSAMP) s_idx[pos] = n;
        cnt += (int)__popcll(m);
    }
    if (cnt > NSAMP) cnt = NSAMP;
    int nb = (lane < cnt) ? s_idx[lane] : -1;
    float nx_ = 0.f, ny_ = 0.f, nz_ = 0.f;
    if (nb >= 0) { nx_ = xb[nb]; ny_ = xb[NPTS + nb]; nz_ = xb[2 * NPTS + nb]; }
    float fx = nx_ - qx, fy = ny_ - qy, fz = nz_ - qz;
    int row = (nb < 0) ? (NPTS - 1) : nb;

    float h1[64];
#pragma unroll
    for (int o = 0; o < 64; o++) {
        float a = __builtin_fmaf(w0[o * INCH + 0], fx, b0[o]);
        a = __builtin_fmaf(w0[o * INCH + 1], fy, a);
        h1[o] = __builtin_fmaf(w0[o * INCH + 2], fz, a);
    }
    const float* pb = pts + (size_t)b * DFEAT * NPTS + row;
#pragma unroll 1
    for (int c = 0; c < 64; c++) {
        float f = pb[(size_t)c * NPTS];
#pragma unroll
        for (int o = 0; o < 64; o++)
            h1[o] = __builtin_fmaf(w0[o * INCH + 3 + c], f, h1[o]);
    }
#pragma unroll
    for (int c = 0; c < 32; c++) s_h[c * 64 + lane] = fmaxf(h1[c], 0.0f);
    float h1h[32];
#pragma unroll
    for (int c = 0; c < 32; c++) h1h[c] = fmaxf(h1[32 + c], 0.0f);

    float h2[64];
#pragma unroll
    for (int o = 0; o < 64; o++) h2[o] = b1[o];
#pragma unroll 1
    for (int c = 0; c < 32; c++) {
        float hc = s_h[c * 64 + lane];
#pragma unroll
        for (int o = 0; o < 64; o++)
            h2[o] = __builtin_fmaf(w1[o * 64 + c], hc, h2[o]);
    }
#pragma unroll
    for (int c = 0; c < 32; c++) s_h[c * 64 + lane] = h1h[c];
#pragma unroll 1
    for (int c = 0; c < 32; c++) {
        float hc = s_h[c * 64 + lane];
#pragma unroll
        for (int o = 0; o < 64; o++)
            h2[o] = __builtin_fmaf(w1[o * 64 + (32 + c)], hc, h2[o]);
    }
#pragma unroll
    for (int o = 0; o < 64; o++) h2[o] = fmaxf(h2[o], 0.0f);

#pragma unroll 2
    for (int o = 0; o < 128; o++) {
        const float* wr = w2 + o * 64;
        float acc = b2[o];
#pragma unroll
        for (int c = 0; c < 64; c++) acc = __builtin_fmaf(wr[c], h2[c], acc);
        acc = fmaxf(acc, 0.0f);
#pragma unroll
        for (int off = 32; off >= 1; off >>= 1)
            acc = fmaxf(acc, __shfl_down(acc, off));
        if (lane == 0) out1[((size_t)(b * 128 + o)) * S_TOT + sg] = acc;
    }
}

extern "C" void kernel_launch(void* const* d_in, const int* in_sizes, int n_in,
                              void* d_out, int out_size, void* d_ws, size_t ws_size,
                              hipStream_t stream) {
    const float* xyz  = (const float*)d_in[0];
    const float* pts  = (const float*)d_in[1];
    const float* attn = (const float*)d_in[2];
    const float* w0 = (const float*)d_in[3];
    const float* b0 = (const float*)d_in[4];
    const float* w1 = (const float*)d_in[5];
    const float* b1 = (const float*)d_in[6];
    const float* w2 = (const float*)d_in[7];
    const float* b2 = (const float*)d_in[8];

    float* out0 = (float*)d_out;                    // [B,3,S]
    float* out1 = out0 + (size_t)NB * 3 * S_TOT;    // [B,128,S]
    float* out2 = out1 + (size_t)NB * 128 * S_TOT;  // [B,1,S]

    // ws: wp (36 tiles * 1KB) | ptsTh bf16 [B][N][64] | cxyz | hdr
    unsigned short* wp    = (unsigned short*)d_ws;
    unsigned short* ptsTh = (unsigned short*)((char*)d_ws + 36864);
    float4*         cxyz  = (float4*)((char*)d_ws + 36864 + 8388608);
    int*            hdr   = (int*)((char*)cxyz + (size_t)16 * CCAP * 16);
    const size_t need = 36864 + 8388608 + (size_t)16 * CCAP * 16 + 128;

    if (ws_size >= need) {
        front_kernel<<<16 + 1024 + 36, 1024, 0, stream>>>(
            xyz, attn, cxyz, hdr, pts, ptsTh, w0, w1, w2, wp);
        fps_iter<<<16, 256, 0, stream>>>(attn, cxyz, hdr, out0, out2);
        fps_kernel<<<16, 1024, 0, stream>>>(xyz, attn, hdr, out0, out2);  // gated
        ball_mlp_mfma<<<NB * S_TOT, 64, 0, stream>>>(xyz, ptsTh, wp, b0, b1, b2,
                                                     out0, out1);
    } else {
        fps_kernel<<<16, 1024, 0, stream>>>(xyz, attn, nullptr, out0, out2);
        ball_mlp_fb<<<NB * S_TOT, 64, 0, stream>>>(xyz, pts, w0, b0, w1, b1,
                                                   w2, b2, out0, out1);
    }
}

// Round 13
// 632.562 us; speedup vs baseline: 1.1885x; 1.1885x over previous
//
#include <hip/hip_runtime.h>
#include <cstdint>
#include <cstddef>

#define NB 8
#define NPTS 8192
#define S_TOT 512
#define NSAMP 64
#define DFEAT 64
#define INCH 67
#define SLOTS 17
#define CCAP (SLOTS * 256)   // 4352 compacted slots per (b,grp)

typedef __attribute__((ext_vector_type(8))) short v8s;
typedef __attribute__((ext_vector_type(4))) short v4s;
typedef __attribute__((ext_vector_type(4))) float v4f;

// exact (numpy-matching) squared distance: (a-b) per component, square, sum as (x+y)+z
__device__ __forceinline__ float d2_exact(float ax, float ay, float az,
                                          float bx, float by, float bz) {
    float dx = __fsub_rn(ax, bx);
    float dy = __fsub_rn(ay, by);
    float dz = __fsub_rn(az, bz);
    return __fadd_rn(__fadd_rn(__fmul_rn(dx, dx), __fmul_rn(dy, dy)), __fmul_rn(dz, dz));
}

// fp32 -> bf16 round-to-nearest-even
__device__ __forceinline__ unsigned short f2b(float f) {
    unsigned u = __float_as_uint(f);
    return (unsigned short)((u + 0x7fffu + ((u >> 16) & 1u)) >> 16);
}

template <int CTRL>
__device__ __forceinline__ unsigned long long dpp_max_u64(unsigned long long k) {
    int lo = (int)(unsigned)(k & 0xffffffffull);
    int hi = (int)(unsigned)(k >> 32);
    int slo = __builtin_amdgcn_update_dpp(lo, lo, CTRL, 0xf, 0xf, false);
    int shi = __builtin_amdgcn_update_dpp(hi, hi, CTRL, 0xf, 0xf, false);
    unsigned long long o = ((unsigned long long)(unsigned)shi << 32) | (unsigned)slo;
    return (o > k) ? o : k;
}

// ---------------------------------------------------------------------------
// Compact (R5-R12-verified): 16 blocks, must precede fps_fused (hdr/cxyz dep).
// ---------------------------------------------------------------------------
__global__ __launch_bounds__(1024) void fps_compact(
    const float* __restrict__ xyz, const float* __restrict__ attn,
    float4* __restrict__ cxyz, int* __restrict__ hdr)
{
    int blk = blockIdx.x;
    int b = blk >> 1, grp = blk & 1;
    const float* xb = xyz + (size_t)b * 3 * NPTS;
    const float* ab = attn + (size_t)b * NPTS;
    float4* c4 = cxyz + (size_t)blk * CCAP;

    int tid = threadIdx.x, lane = tid & 63, wid = tid >> 6;
    int n0 = tid * 8;

    __shared__ int s_repmin;
    __shared__ int s_ws[16];
    if (tid == 0) s_repmin = NPTS;
    __syncthreads();

    float av[8];
    *(float4*)&av[0] = *(const float4*)(ab + n0);
    *(float4*)&av[4] = *(const float4*)(ab + n0 + 4);
    int cnt = 0, mymin = NPTS;
    bool keep[8];
#pragma unroll
    for (int j = 0; j < 8; j++) {
        keep[j] = grp ? (av[j] == 0.0f) : (av[j] != 0.0f);
        cnt += keep[j] ? 1 : 0;
        if (!keep[j] && n0 + j < mymin) mymin = n0 + j;
    }
    if (mymin < NPTS) atomicMin(&s_repmin, mymin);

    int incl = cnt;
#pragma unroll
    for (int off = 1; off <= 32; off <<= 1) {
        int t = __shfl_up(incl, off);
        if (lane >= off) incl += t;
    }
    if (lane == 63) s_ws[wid] = incl;
    __syncthreads();
    int woff = 0, tot = 0;
#pragma unroll
    for (int w = 0; w < 16; w++) { if (w < wid) woff += s_ws[w]; tot += s_ws[w]; }
    int pos = woff + incl - cnt;
    int rm = s_repmin;
    int rm_eff = (rm < NPTS) ? rm : 0x7fffffff;

    float xv[8], yv[8], zv[8];
    *(float4*)&xv[0] = *(const float4*)(xb + n0);
    *(float4*)&xv[4] = *(const float4*)(xb + n0 + 4);
    *(float4*)&yv[0] = *(const float4*)(xb + NPTS + n0);
    *(float4*)&yv[4] = *(const float4*)(xb + NPTS + n0 + 4);
    *(float4*)&zv[0] = *(const float4*)(xb + 2 * NPTS + n0);
    *(float4*)&zv[4] = *(const float4*)(xb + 2 * NPTS + n0 + 4);
#pragma unroll
    for (int j = 0; j < 8; j++) {
        if (keep[j]) {
            int fin = pos + ((n0 + j > rm_eff) ? 1 : 0);
            if (fin < CCAP)
                c4[fin] = make_float4(xv[j], yv[j], zv[j], 0.0f);
            pos++;
        }
    }
    if (tid == 0) {
        int M = tot;
        if (rm < NPTS) {
            if (rm < CCAP)
                c4[rm] = make_float4(__fmul_rn(0.0f, xb[rm]),
                                     __fmul_rn(0.0f, xb[NPTS + rm]),
                                     __fmul_rn(0.0f, xb[2 * NPTS + rm]), 0.0f);
            M++;
        }
        hdr[blk * 2] = M;
        hdr[blk * 2 + 1] = (rm < NPTS) ? rm : -1;
    }
}

// ---------------------------------------------------------------------------
// FUSED: blocks 0..15 = fps_iter (EXACT R10 barrier version — 463 us, VGPR 88;
// six restructures R3/R4/R7/R8/R11/R12 all failed to beat it; R12 proved
// s_barrier is cheap and spin-poll is worse). Blocks 16..1039 = points
// transpose; blocks 1040..1075 = weight pack. Prep blocks have NO dependency
// on fps blocks (no deadlock possible) and run on the ~240 CUs that idle
// during FPS — removes the serialized front-kernel stage (~20-25 us).
// LDS is a ~76 KB char union: fps uses sc/obuf/red, transpose uses a 64x65
// fp32 tile.
// ---------------------------------------------------------------------------
__global__ __launch_bounds__(256, 1) void fps_fused(
    const float* __restrict__ attn,
    const float4* __restrict__ cxyz,
    const int* __restrict__ hdr,
    float* __restrict__ out0, float* __restrict__ out2,
    const float* __restrict__ pts, unsigned short* __restrict__ ptsTh,
    const float* __restrict__ w0, const float* __restrict__ w1,
    const float* __restrict__ w2, unsigned short* __restrict__ wp)
{
    __shared__ __align__(16) char smem[69632 + 6144 + 64];
    int blk = blockIdx.x;
    int tid = threadIdx.x;

    if (blk < 16) {
        // ---------------- fps_iter (R10-exact) ----------------
        int b = blk >> 1, grp = blk & 1;
        int K = grp ? 384 : 128;
        int soff = grp ? 128 : 0;
        int M = hdr[blk * 2];
        int repslot = hdr[blk * 2 + 1];
        if (M > CCAP) return;             // fps_kernel fallback covers this block
        int lane = tid & 63, wid = tid >> 6;

        const float4* cb = cxyz + (size_t)blk * CCAP;
        float4* sc = (float4*)smem;                                   // [CCAP]
        float4* s_obuf = (float4*)(smem + 69632);                     // [384]
        unsigned long long* s_red = (unsigned long long*)(smem + 69632 + 6144); // [2][4]

        float px[SLOTS], py[SLOTS], pz[SLOTS], md[SLOTS];
#pragma unroll
        for (int i = 0; i < SLOTS; i++) {
            int sl = i * 256 + tid;
            bool v = sl < M;
            float4 c = v ? cb[sl] : make_float4(0.f, 0.f, 0.f, 0.f);
            px[i] = c.x; py[i] = c.y; pz[i] = c.z;
            sc[sl] = c;
            md[i] = v ? 1e10f : -1.0f;
        }
        float4 c0 = cb[0];
        float lx = c0.x, ly = c0.y, lz = c0.z;
        float a_last = attn[(size_t)b * NPTS];
        float kept_a = grp ? 0.0f : 1.0f;
        float rep_a  = grp ? 1.0f : 0.0f;

        for (int k = 0; k < K; k++) {
            if (tid == 0) s_obuf[k] = make_float4(lx, ly, lz, a_last);
            if (k == K - 1) break;

            float bv = -1.0f; int bslot = 0x7fffffff;
#pragma unroll
            for (int i = 0; i < SLOTS; i++) {
                float d2 = d2_exact(px[i], py[i], pz[i], lx, ly, lz);
                md[i] = fminf(md[i], d2);
                int sl = i * 256 + tid;
                bool w = (md[i] > bv) || ((md[i] == bv) && (sl < bslot));
                bv = w ? md[i] : bv;
                bslot = w ? sl : bslot;
            }
            unsigned long long key = (bv >= 0.0f)
                ? (((unsigned long long)__float_as_uint(bv) << 32) | (unsigned)(~bslot))
                : 0ull;
            key = dpp_max_u64<0x111>(key);
            key = dpp_max_u64<0x112>(key);
            key = dpp_max_u64<0x114>(key);
            key = dpp_max_u64<0x118>(key);
            key = dpp_max_u64<0x142>(key);
            key = dpp_max_u64<0x143>(key);    // lane 63 = wave max
            int buf = k & 1;
            if (lane == 63) s_red[buf * 4 + wid] = key;
            __syncthreads();                  // lgkm-only drain (no global ops in flight)

            const unsigned long long* rp = &s_red[buf * 4];
            unsigned long long k0 = rp[0], k1 = rp[1], k2 = rp[2], k3 = rp[3];
            unsigned long long m01 = (k0 > k1) ? k0 : k1;
            unsigned long long m23 = (k2 > k3) ? k2 : k3;
            unsigned long long g = (m01 > m23) ? m01 : m23;
            int wslot = (int)(~(unsigned)g);
            float4 wc = sc[wslot];            // ds_read_b128, broadcast
            lx = wc.x; ly = wc.y; lz = wc.z;
            a_last = (wslot == repslot) ? rep_a : kept_a;
        }
        __syncthreads();
        for (int k2i = tid; k2i < K; k2i += 256) {
            float4 o = s_obuf[k2i];
            int sg = soff + k2i;
            out0[(size_t)b * 3 * S_TOT + sg] = o.x;
            out0[(size_t)b * 3 * S_TOT + S_TOT + sg] = o.y;
            out0[(size_t)b * 3 * S_TOT + 2 * S_TOT + sg] = o.z;
            out2[(size_t)b * S_TOT + sg] = o.w;
        }
    } else if (blk < 16 + 1024) {
        // ---------------- points transpose (256 thr, 64x64 tile) ----------------
        float (*t)[65] = (float(*)[65])smem;   // 16.6 KB of the union
        int blk2 = blk - 16;
        int b = blk2 >> 7;
        int n0 = (blk2 & 127) * 64;
        int tx = tid & 63, ty = tid >> 6;      // ty in 0..3
        for (int c = ty; c < 64; c += 4)
            t[c][tx] = pts[((size_t)b * DFEAT + c) * NPTS + n0 + tx];
        __syncthreads();
        for (int r = ty; r < 64; r += 4)
            ptsTh[((size_t)b * NPTS + n0 + r) * DFEAT + tx] = f2b(t[tx][r]);
    } else if (tid < 64) {
        // ---------------- weight pack ----------------
        int t = blk - (16 + 1024), l = tid;
        int kq = (l >> 4) * 8, n16 = l & 15;
        unsigned short o[8];
#pragma unroll
        for (int j = 0; j < 8; j++) {
            float v;
            if (t < 12) {
                int kt = t >> 2, nt = t & 3;
                int k = kt * 32 + kq + j, n = nt * 16 + n16;
                v = (k < 64) ? w0[n * INCH + 3 + k] : (k < 67 ? w0[n * INCH + (k - 64)] : 0.0f);
            } else if (t < 20) {
                int tt = t - 12, kt = tt >> 2, nt = tt & 3;
                v = w1[(nt * 16 + n16) * 64 + kt * 32 + kq + j];
            } else {
                int tt = t - 20, kt = tt >> 3, nt = tt & 7;
                v = w2[(nt * 16 + n16) * 64 + kt * 32 + kq + j];
            }
            o[j] = f2b(v);
        }
        *(v8s*)&wp[(size_t)t * 512 + l * 8] = *(v8s*)o;
    }
}

// ---------------------------------------------------------------------------
// Fallback FPS (unchanged): only if a block overflowed CCAP or ws too small.
// ---------------------------------------------------------------------------
__global__ __launch_bounds__(1024, 1) void fps_kernel(
    const float* __restrict__ xyz, const float* __restrict__ attn,
    const int* __restrict__ hdr,
    float* __restrict__ out0, float* __restrict__ out2)
{
    int blk = blockIdx.x;
    if (hdr != nullptr && hdr[blk * 2] <= CCAP) return;
    int b = blk >> 1, grp = blk & 1;
    int K = grp ? 384 : 128;
    int soff = grp ? 128 : 0;
    int tid = threadIdx.x, lane = tid & 63, wid = tid >> 6;
    const float* xb = xyz + (size_t)b * 3 * NPTS;
    const float* ab = attn + (size_t)b * NPTS;

    float px[8], py[8], pz[8], md[8];
#pragma unroll
    for (int i = 0; i < 8; i++) {
        int n = tid + i * 1024;
        float a = ab[n];
        float f = grp ? __fsub_rn(1.0f, a) : a;
        px[i] = __fmul_rn(f, xb[n]);
        py[i] = __fmul_rn(f, xb[NPTS + n]);
        pz[i] = __fmul_rn(f, xb[2 * NPTS + n]);
        md[i] = 1e10f;
    }
    __shared__ unsigned long long s_red[2][16];
    float a_last = ab[0];
    float f0 = grp ? __fsub_rn(1.0f, a_last) : a_last;
    float lx = __fmul_rn(f0, xb[0]);
    float ly = __fmul_rn(f0, xb[NPTS]);
    float lz = __fmul_rn(f0, xb[2 * NPTS]);

    for (int k = 0; k < K; k++) {
        if (tid == 0) {
            int sg = soff + k;
            out0[(size_t)b * 3 * S_TOT + sg] = lx;
            out0[(size_t)b * 3 * S_TOT + S_TOT + sg] = ly;
            out0[(size_t)b * 3 * S_TOT + 2 * S_TOT + sg] = lz;
            out2[(size_t)b * S_TOT + sg] = a_last;
        }
        if (k == K - 1) break;
        float bv = -1.0f; int bi = 0;
#pragma unroll
        for (int i = 0; i < 8; i++) {
            float d2 = d2_exact(px[i], py[i], pz[i], lx, ly, lz);
            md[i] = fminf(md[i], d2);
            if (md[i] > bv) { bv = md[i]; bi = tid + i * 1024; }
        }
        unsigned long long best =
            ((unsigned long long)__float_as_uint(bv) << 32) | (unsigned)(~bi);
#pragma unroll
        for (int off = 32; off >= 1; off >>= 1) {
            unsigned long long o = __shfl_down(best, off);
            best = (o > best) ? o : best;
        }
        if (lane == 0) s_red[k & 1][wid] = best;
        __syncthreads();
        unsigned long long r = (lane < 16) ? s_red[k & 1][lane] : 0ull;
#pragma unroll
        for (int off = 8; off >= 1; off >>= 1) {
            unsigned long long o = __shfl_down(r, off);
            r = (o > r) ? o : r;
        }
        r = __shfl(r, 0);
        int n = (int)(~(unsigned)r);
        a_last = ab[n];
        float fl = grp ? __fsub_rn(1.0f, a_last) : a_last;
        lx = __fmul_rn(fl, xb[n]);
        ly = __fmul_rn(fl, xb[NPTS + n]);
        lz = __fmul_rn(fl, xb[2 * NPTS + n]);
    }
}

// ---------------------------------------------------------------------------
// Ball query + MFMA MLP + max. UNCHANGED from R10 (verified absmax 0.015625;
// LDS union 13.6 KB).
// ---------------------------------------------------------------------------
__global__ __launch_bounds__(64, 2) void ball_mlp_mfma(
    const float* __restrict__ xyz,
    const unsigned short* __restrict__ ptsTh,
    const unsigned short* __restrict__ wp,
    const float* __restrict__ b0, const float* __restrict__ b1,
    const float* __restrict__ b2,
    const float* __restrict__ out0,
    float* __restrict__ out1)
{
    const float R2 = (float)(0.4 * 0.4);   // 0x3E23D70A — NOT 0.4f*0.4f
    int q = blockIdx.x;
    int b = q >> 9;
    int sg = q & 511;
    int lane = threadIdx.x;
    int col = lane & 15, quad = lane >> 4, kq = quad * 8;

    const float* xb = xyz + (size_t)b * 3 * NPTS;
    float qx = out0[(size_t)b * 3 * S_TOT + sg];
    float qy = out0[(size_t)b * 3 * S_TOT + S_TOT + sg];
    float qz = out0[(size_t)b * 3 * S_TOT + 2 * S_TOT + sg];

    __shared__ int s_idx[NSAMP];
    __shared__ __align__(16) short sBuf[64 * 104];           // 13312 B union
    unsigned long long* s_mask = (unsigned long long*)sBuf;  // phase A: 1 KB

    // ---- phase 1: independent ballots ----
#pragma unroll 8
    for (int j = 0; j < 128; j++) {
        int n = j * 64 + lane;
        float d2 = d2_exact(qx, qy, qz, xb[n], xb[NPTS + n], xb[2 * NPTS + n]);
        unsigned long long m = __ballot(d2 < R2);
        if (lane == 0) s_mask[j] = m;
    }

    // ---- phase 2: prefix over 128 chunk popcounts ----
    unsigned long long m0 = s_mask[lane];
    unsigned long long m1 = s_mask[64 + lane];
    int c0 = (int)__popcll(m0), c1 = (int)__popcll(m1);
    int i0 = c0;
#pragma unroll
    for (int off = 1; off <= 32; off <<= 1) {
        int t = __shfl_up(i0, off);
        if (lane >= off) i0 += t;
    }
    int T0 = __shfl(i0, 63);
    int i1 = c1;
#pragma unroll
    for (int off = 1; off <= 32; off <<= 1) {
        int t = __shfl_up(i1, off);
        if (lane >= off) i1 += t;
    }
    int total = T0 + __shfl(i1, 63);
    int p0 = i0 - c0;
    int p1 = T0 + i1 - c1;

    // ---- phase 3: bit expansion into s_idx (global chunk/bit order) ----
    {
        int base = p0, org = lane * 64;
        while (m0 && base < NSAMP) {
            int bp = __ffsll((long long)m0) - 1;
            s_idx[base++] = org + bp;
            m0 &= m0 - 1;
        }
        base = p1; org = (64 + lane) * 64;
        while (m1 && base < NSAMP) {
            int bp = __ffsll((long long)m1) - 1;
            s_idx[base++] = org + bp;
            m1 &= m1 - 1;
        }
    }
    int cnt = (total > NSAMP) ? NSAMP : total;

    int nb = (lane < cnt) ? s_idx[lane] : -1;
    float nx_ = 0.f, ny_ = 0.f, nz_ = 0.f;
    if (nb >= 0) { nx_ = xb[nb]; ny_ = xb[NPTS + nb]; nz_ = xb[2 * NPTS + nb]; }
    float fx = nx_ - qx, fy = ny_ - qy, fz = nz_ - qz;   // pad rows: -new_xyz
    int row = (nb < 0) ? (NPTS - 1) : nb;                // torch -1 wraps to last

    // ---- stage X1 row (stride 104; masks dead, safe to overwrite) ----
    {
        const unsigned short* ph = ptsTh + ((size_t)b * NPTS + row) * DFEAT;
        short* xr = &sBuf[lane * 104];
#pragma unroll
        for (int i = 0; i < 8; i++)
            *(v8s*)(xr + i * 8) = *(const v8s*)(ph + i * 8);
#pragma unroll
        for (int i = 0; i < 5; i++)
            *(v8s*)(xr + 64 + i * 8) = (v8s)0;
        v4s xyzp;
        xyzp[0] = (short)f2b(fx); xyzp[1] = (short)f2b(fy);
        xyzp[2] = (short)f2b(fz); xyzp[3] = 0;
        *(v4s*)(xr + 64) = xyzp;
    }

    const v8s* wpv = (const v8s*)wp;

    // ---- layer 1: [64x96] x [96x64], 3 K-steps ----
    v4f acc[4][4];
#pragma unroll
    for (int nt = 0; nt < 4; nt++) {
        float bb = b0[nt * 16 + col];
#pragma unroll
        for (int mt = 0; mt < 4; mt++) acc[mt][nt] = (v4f){bb, bb, bb, bb};
    }
#pragma unroll
    for (int kt = 0; kt < 3; kt++) {
        v8s bf[4];
#pragma unroll
        for (int nt = 0; nt < 4; nt++) bf[nt] = wpv[(kt * 4 + nt) * 64 + lane];
#pragma unroll
        for (int mt = 0; mt < 4; mt++) {
            v8s a = *(const v8s*)&sBuf[(mt * 16 + col) * 104 + kt * 32 + kq];
#pragma unroll
            for (int nt = 0; nt < 4; nt++)
                acc[mt][nt] = __builtin_amdgcn_mfma_f32_16x16x32_bf16(a, bf[nt], acc[mt][nt], 0, 0, 0);
        }
    }
#pragma unroll
    for (int mt = 0; mt < 4; mt++)
#pragma unroll
        for (int nt = 0; nt < 4; nt++)
#pragma unroll
            for (int r = 0; r < 4; r++)
                sBuf[(mt * 16 + quad * 4 + r) * 72 + nt * 16 + col] =
                    (short)f2b(fmaxf(acc[mt][nt][r], 0.0f));

    // ---- layer 2: [64x64] x [64x64], 2 K-steps ----
#pragma unroll
    for (int nt = 0; nt < 4; nt++) {
        float bb = b1[nt * 16 + col];
#pragma unroll
        for (int mt = 0; mt < 4; mt++) acc[mt][nt] = (v4f){bb, bb, bb, bb};
    }
#pragma unroll
    for (int kt = 0; kt < 2; kt++) {
        v8s bf[4];
#pragma unroll
        for (int nt = 0; nt < 4; nt++) bf[nt] = wpv[(12 + kt * 4 + nt) * 64 + lane];
#pragma unroll
        for (int mt = 0; mt < 4; mt++) {
            v8s a = *(const v8s*)&sBuf[(mt * 16 + col) * 72 + kt * 32 + kq];
#pragma unroll
            for (int nt = 0; nt < 4; nt++)
                acc[mt][nt] = __builtin_amdgcn_mfma_f32_16x16x32_bf16(a, bf[nt], acc[mt][nt], 0, 0, 0);
        }
    }
#pragma unroll
    for (int mt = 0; mt < 4; mt++)
#pragma unroll
        for (int nt = 0; nt < 4; nt++)
#pragma unroll
            for (int r = 0; r < 4; r++)
                sBuf[(mt * 16 + quad * 4 + r) * 72 + nt * 16 + col] =
                    (short)f2b(fmaxf(acc[mt][nt][r], 0.0f));

    // ---- layer 3: [64x64] x [64x128], two passes of 4 N-tiles ----
#pragma unroll
    for (int p = 0; p < 2; p++) {
#pragma unroll
        for (int nt = 0; nt < 4; nt++) {
            float bb = b2[(p * 4 + nt) * 16 + col];
#pragma unroll
            for (int mt = 0; mt < 4; mt++) acc[mt][nt] = (v4f){bb, bb, bb, bb};
        }
#pragma unroll
        for (int kt = 0; kt < 2; kt++) {
            v8s bf[4];
#pragma unroll
            for (int nt = 0; nt < 4; nt++)
                bf[nt] = wpv[(20 + kt * 8 + p * 4 + nt) * 64 + lane];
#pragma unroll
            for (int mt = 0; mt < 4; mt++) {
                v8s a = *(const v8s*)&sBuf[(mt * 16 + col) * 72 + kt * 32 + kq];
#pragma unroll
                for (int nt = 0; nt < 4; nt++)
                    acc[mt][nt] = __builtin_amdgcn_mfma_f32_16x16x32_bf16(a, bf[nt], acc[mt][nt], 0, 0, 0);
            }
        }
#pragma unroll
        for (int nt = 0; nt < 4; nt++) {
            float v = 0.0f;   // relu output >= 0
#pragma unroll
            for (int mt = 0; mt < 4; mt++)
#pragma unroll
                for (int r = 0; r < 4; r++)
                    v = fmaxf(v, acc[mt][nt][r]);
            v = fmaxf(v, __shfl_xor(v, 16));
            v = fmaxf(v, __shfl_xor(v, 32));
            if (lane < 16)
                out1[((size_t)(b * 128 + (p * 4 + nt) * 16 + lane)) * S_TOT + sg] = v;
        }
    }
}

// ---------------------------------------------------------------------------
// Fallback ball+MLP (no ws): unchanged from R6.
// ---------------------------------------------------------------------------
__global__ __launch_bounds__(64, 1) void ball_mlp_fb(
    const float* __restrict__ xyz, const float* __restrict__ pts,
    const float* __restrict__ w0, const float* __restrict__ b0,
    const float* __restrict__ w1, const float* __restrict__ b1,
    const float* __restrict__ w2, const float* __restrict__ b2,
    const float* __restrict__ out0, float* __restrict__ out1)
{
    const float R2 = (float)(0.4 * 0.4);
    int q = blockIdx.x;
    int b = q >> 9, sg = q & 511, lane = threadIdx.x;
    const float* xb = xyz + (size_t)b * 3 * NPTS;
    float qx = out0[(size_t)b * 3 * S_TOT + sg];
    float qy = out0[(size_t)b * 3 * S_TOT + S_TOT + sg];
    float qz = out0[(size_t)b * 3 * S_TOT + 2 * S_TOT + sg];

    __shared__ int s_idx[NSAMP];
    __shared__ float s_h[32 * 64];
    int cnt = 0;
    for (int base = 0; base < NPTS; base += 64) {
        int n = base + lane;
        float d2 = d2_exact(qx, qy, qz, xb[n], xb[NPTS + n], xb[2 * NPTS + n]);
        bool flag = d2 < R2;
        unsigned long long m = __ballot(flag);
        int pos = cnt + (int)__popcll(m & ((1ull << lane) - 1ull));
        if (flag && pos < NSAMP) s_idx[pos] = n;
        cnt += (int)__popcll(m);
    }
    if (cnt > NSAMP) cnt = NSAMP;
    int nb = (lane < cnt) ? s_idx[lane] : -1;
    float nx_ = 0.f, ny_ = 0.f, nz_ = 0.f;
    if (nb >= 0) { nx_ = xb[nb]; ny_ = xb[NPTS + nb]; nz_ = xb[2 * NPTS + nb]; }
    float fx = nx_ - qx, fy = ny_ - qy, fz = nz_ - qz;
    int row = (nb < 0) ? (NPTS - 1) : nb;

    float h1[64];
#pragma unroll
    for (int o = 0; o < 64; o++) {
        float a = __builtin_fmaf(w0[o * INCH + 0], fx, b0[o]);
        a = __builtin_fmaf(w0[o * INCH + 1], fy, a);
        h1[o] = __builtin_fmaf(w0[o * INCH + 2], fz, a);
    }
    const float* pb = pts + (size_t)b * DFEAT * NPTS + row;
#pragma unroll 1
    for (int c = 0; c < 64; c++) {
        float f = pb[(size_t)c * NPTS];
#pragma unroll
        for (int o = 0; o < 64; o++)
            h1[o] = __builtin_fmaf(w0[o * INCH + 3 + c], f, h1[o]);
    }
#pragma unroll
    for (int c = 0; c < 32; c++) s_h[c * 64 + lane] = fmaxf(h1[c], 0.0f);
    float h1h[32];
#pragma unroll
    for (int c = 0; c < 32; c++) h1h[c] = fmaxf(h1[32 + c], 0.0f);

    float h2[64];
#pragma unroll
    for (int o = 0; o < 64; o++) h2[o] = b1[o];
#pragma unroll 1
    for (int c = 0; c < 32; c++) {
        float hc = s_h[c * 64 + lane];
#pragma unroll
        for (int o = 0; o < 64; o++)
            h2[o] = __builtin_fmaf(w1[o * 64 + c], hc, h2[o]);
    }
#pragma unroll
    for (int c = 0; c < 32; c++) s_h[c * 64 + lane] = h1h[c];
#pragma unroll 1
    for (int c = 0; c < 32; c++) {
        float hc = s_h[c * 64 + lane];
#pragma unroll
        for (int o = 0; o < 64; o++)
            h2[o] = __builtin_fmaf(w1[o * 64 + (32 + c)], hc, h2[o]);
    }
#pragma unroll
    for (int o = 0; o < 64; o++) h2[o] = fmaxf(h2[o], 0.0f);

#pragma unroll 2
    for (int o = 0; o < 128; o++) {
        const float* wr = w2 + o * 64;
        float acc = b2[o];
#pragma unroll
        for (int c = 0; c < 64; c++) acc = __builtin_fmaf(wr[c], h2[c], acc);
        acc = fmaxf(acc, 0.0f);
#pragma unroll
        for (int off = 32; off >= 1; off >>= 1)
            acc = fmaxf(acc, __shfl_down(acc, off));
        if (lane == 0) out1[((size_t)(b * 128 + o)) * S_TOT + sg] = acc;
    }
}

extern "C" void kernel_launch(void* const* d_in, const int* in_sizes, int n_in,
                              void* d_out, int out_size, void* d_ws, size_t ws_size,
                              hipStream_t stream) {
    const float* xyz  = (const float*)d_in[0];
    const float* pts  = (const float*)d_in[1];
    const float* attn = (const float*)d_in[2];
    const float* w0 = (const float*)d_in[3];
    const float* b0 = (const float*)d_in[4];
    const float* w1 = (const float*)d_in[5];
    const float* b1 = (const float*)d_in[6];
    const float* w2 = (const float*)d_in[7];
    const float* b2 = (const float*)d_in[8];

    float* out0 = (float*)d_out;                    // [B,3,S]
    float* out1 = out0 + (size_t)NB * 3 * S_TOT;    // [B,128,S]
    float* out2 = out1 + (size_t)NB * 128 * S_TOT;  // [B,1,S]

    // ws: wp (36 tiles * 1KB) | ptsTh bf16 [B][N][64] | cxyz | hdr
    unsigned short* wp    = (unsigned short*)d_ws;
    unsigned short* ptsTh = (unsigned short*)((char*)d_ws + 36864);
    float4*         cxyz  = (float4*)((char*)d_ws + 36864 + 8388608);
    int*            hdr   = (int*)((char*)cxyz + (size_t)16 * CCAP * 16);
    const size_t need = 36864 + 8388608 + (size_t)16 * CCAP * 16 + 128;

    if (ws_size >= need) {
        fps_compact<<<16, 1024, 0, stream>>>(xyz, attn, cxyz, hdr);
        fps_fused<<<16 + 1024 + 36, 256, 0, stream>>>(
            attn, cxyz, hdr, out0, out2, pts, ptsTh, w0, w1, w2, wp);
        fps_kernel<<<16, 1024, 0, stream>>>(xyz, attn, hdr, out0, out2);  // gated
        ball_mlp_mfma<<<NB * S_TOT, 64, 0, stream>>>(xyz, ptsTh, wp, b0, b1, b2,
                                                     out0, out1);
    } else {
        fps_kernel<<<16, 1024, 0, stream>>>(xyz, attn, nullptr, out0, out2);
        ball_mlp_fb<<<NB * S_TOT, 64, 0, stream>>>(xyz, pts, w0, b0, w1, b1,
                                                   w2, b2, out0, out1);
    }
}